// Round 5
// baseline (283.787 us; speedup 1.0000x reference)
//
#include <hip/hip_runtime.h>
#include <cstddef>

#define L_SEQ 784
#define DIM 384
#define B_SZ 16
#define NH 8
#define QKD 32
#define VD 128
#define EDIM 1536   // NH*(2*QKD+VD)
#define RESN 25
#define NPTS 625    // RESN*RESN
#define ODIM 1024   // NH*VD
#define NQT 13      // ceil(784/64) q-tiles
#define NKT 13      // ceil(784/64) k-tiles
#define QKVD 192    // 2*QKD + VD

typedef short s16x8 __attribute__((ext_vector_type(8)));
typedef short s16x4 __attribute__((ext_vector_type(4)));
typedef float f32x4v __attribute__((ext_vector_type(4)));

__device__ __forceinline__ short f2bf(float f) {
    union { float f; unsigned u; } c; c.f = f;
    unsigned u = c.u;
    return (short)((u + 0x7FFFu + ((u >> 16) & 1u)) >> 16);
}

__device__ __forceinline__ s16x8 ld_frag(const short* p) {
    s16x4 lo = *(const s16x4*)p;
    s16x4 hi = *(const s16x4*)(p + 4);
    s16x8 r;
    r[0] = lo[0]; r[1] = lo[1]; r[2] = lo[2]; r[3] = lo[3];
    r[4] = hi[0]; r[5] = hi[1]; r[6] = hi[2]; r[7] = hi[3];
    return r;
}

__device__ __forceinline__ void st_frag(short* p, s16x8 w) {
    s16x4 lo, hi;
    lo[0] = w[0]; lo[1] = w[1]; lo[2] = w[2]; lo[3] = w[3];
    hi[0] = w[4]; hi[1] = w[5]; hi[2] = w[6]; hi[3] = w[7];
    *(s16x4*)p = lo;
    *(s16x4*)(p + 4) = hi;
}

// Raw workgroup barrier that does NOT drain vmcnt (global prefetches stay in
// flight); waits only this wave's LDS ops, then s_barrier.
__device__ __forceinline__ void wg_barrier_lds() {
    asm volatile("s_waitcnt lgkmcnt(0)" ::: "memory");
    __builtin_amdgcn_s_barrier();
    asm volatile("" ::: "memory");
}

// ---------------------------------------------------------------------------
// fp32 -> bf16 bulk convert, all three tensors in ONE launch (8 elts/thread)
// ---------------------------------------------------------------------------
__global__ __launch_bounds__(256) void cvt_bf16_all(const float* __restrict__ s0, short* __restrict__ d0, int n0,
                                                    const float* __restrict__ s1, short* __restrict__ d1, int n1,
                                                    const float* __restrict__ s2, short* __restrict__ d2, int n2) {
    int i = blockIdx.x * 256 + threadIdx.x;
    const float* s;
    short* d;
    int li;
    if (i < n0) { s = s0; d = d0; li = i; }
    else if (i < n0 + n1) { s = s1; d = d1; li = i - n0; }
    else if (i < n0 + n1 + n2) { s = s2; d = d2; li = i - n0 - n1; }
    else return;
    const float4* sp = (const float4*)(s + (size_t)li * 8);
    float4 a = sp[0], c = sp[1];
    s16x8 w;
    w[0] = f2bf(a.x); w[1] = f2bf(a.y); w[2] = f2bf(a.z); w[3] = f2bf(a.w);
    w[4] = f2bf(c.x); w[5] = f2bf(c.y); w[6] = f2bf(c.z); w[7] = f2bf(c.w);
    *(s16x8*)(d + (size_t)li * 8) = w;
}

// ---------------------------------------------------------------------------
// cubic interpolation weight (a = -0.75)
// ---------------------------------------------------------------------------
__device__ __forceinline__ float cubic_w(float x) {
    float ax = fabsf(x);
    const float a = -0.75f;
    float w1 = ((a + 2.0f) * ax - (a + 3.0f)) * ax * ax + 1.0f;
    float w2 = a * (((ax - 5.0f) * ax + 8.0f) * ax - 4.0f);
    return ax <= 1.0f ? w1 : (ax < 2.0f ? w2 : 0.0f);
}

__global__ void interp_tab_kernel(float* __restrict__ wtab,
                                  int* __restrict__ iyb,
                                  int* __restrict__ ixb) {
    int o = blockIdx.x * blockDim.x + threadIdx.x;
    if (o >= L_SEQ) return;
    const float scale = 625.0f / 784.0f;
    float src = ((float)o + 0.5f) * scale - 0.5f;
    float f = floorf(src);
    float t = src - f;
    int fi = (int)f;
    float w[4];
    w[0] = cubic_w(t + 1.0f);
    w[1] = cubic_w(t);
    w[2] = cubic_w(1.0f - t);
    w[3] = cubic_w(2.0f - t);
#pragma unroll
    for (int j = 0; j < 4; ++j) {
        int idx = fi - 1 + j;
        idx = idx < 0 ? 0 : (idx > NPTS - 1 ? NPTS - 1 : idx);
        wtab[o * 4 + j] = w[j];
        iyb[o * 4 + j] = idx / RESN;
        ixb[o * 4 + j] = idx % RESN;
    }
}

// ---------------------------------------------------------------------------
// biasT[h][p][o]: per-head table in LDS; 4 o-outputs/thread, float4 store.
// ---------------------------------------------------------------------------
__global__ __launch_bounds__(256) void bias_kernel(const float* __restrict__ table,
                                                   const float* __restrict__ wtab,
                                                   const int* __restrict__ iyb,
                                                   const int* __restrict__ ixb,
                                                   float* __restrict__ biasT) {
    __shared__ float Tl[NPTS];
    const int h = blockIdx.y;
    {
        const float* th = table + (size_t)h * NPTS;
        for (int i = threadIdx.x; i < NPTS; i += 256) Tl[i] = th[i];
    }
    __syncthreads();

    int base = (blockIdx.x * 256 + threadIdx.x) * 4;
    if (base >= L_SEQ * L_SEQ) return;
    int p = base / L_SEQ;
    int o0 = base - p * L_SEQ;

    float4 wpv = *(const float4*)(wtab + p * 4);
    int4 pyv = *(const int4*)(iyb + p * 4);
    int4 pxv = *(const int4*)(ixb + p * 4);
    float wp[4] = {wpv.x, wpv.y, wpv.z, wpv.w};
    int py[4] = {pyv.x, pyv.y, pyv.z, pyv.w};
    int px[4] = {pxv.x, pxv.y, pxv.z, pxv.w};

    float4 res;
    float* rp = (float*)&res;
#pragma unroll
    for (int u = 0; u < 4; ++u) {
        int o = o0 + u;
        float4 wov = *(const float4*)(wtab + o * 4);
        int4 oyv = *(const int4*)(iyb + o * 4);
        int4 oxv = *(const int4*)(ixb + o * 4);
        float wo[4] = {wov.x, wov.y, wov.z, wov.w};
        int oy[4] = {oyv.x, oyv.y, oyv.z, oyv.w};
        int ox[4] = {oxv.x, oxv.y, oxv.z, oxv.w};
        float s = 0.0f;
#pragma unroll
        for (int a = 0; a < 4; ++a) {
#pragma unroll
            for (int b = 0; b < 4; ++b) {
                int dy = abs(oy[a] - py[b]);
                int dx = abs(ox[a] - px[b]);
                s += wo[a] * wp[b] * Tl[dy * RESN + dx];
            }
        }
        rp[u] = s;
    }
    *(float4*)(biasT + (size_t)h * L_SEQ * L_SEQ + base) = res;
}

// ---------------------------------------------------------------------------
// qkv GEMM (bf16 in, 128x128 tile, 2x2 wave quadrants, BK=32).
// Outputs (r3-verified epilogue):
//   qkb[bh][seq][64] : q feats 0..31 (pre-scaled), k feats 32..63
//                      (MFMA-fragment-contiguous for direct global loads)
//   vT [bh][vd][seq] : V transposed (PV staging layout)
// ---------------------------------------------------------------------------
__global__ __launch_bounds__(256) void qkv_gemm_mfma(const short* __restrict__ Xb,
                                                     const short* __restrict__ Wb,
                                                     short* __restrict__ qkb,
                                                     short* __restrict__ vT) {
    __shared__ short Ak[128][48];
    __shared__ short Bk[128][48];

    const int tid = threadIdx.x;
    const int wv = tid >> 6;
    const int lane = tid & 63;
    const int quad = lane >> 4;
    const int l15 = lane & 15;
    const int wr = wv >> 1, wc = wv & 1;
    const int m0 = blockIdx.x * 128;
    const int n0 = blockIdx.y * 128;

    f32x4v acc[4][4];
#pragma unroll
    for (int i = 0; i < 4; ++i)
#pragma unroll
        for (int j = 0; j < 4; ++j) { acc[i][j][0] = 0.f; acc[i][j][1] = 0.f; acc[i][j][2] = 0.f; acc[i][j][3] = 0.f; }

    for (int k0 = 0; k0 < DIM; k0 += 32) {
        __syncthreads();
#pragma unroll
        for (int it = 0; it < 2; ++it) {
            int idx = it * 256 + tid;
            int row = idx >> 2, seg = idx & 3;
            *(s16x8*)&Ak[row][seg * 8] = *(const s16x8*)(Xb + (size_t)(m0 + row) * DIM + k0 + seg * 8);
            *(s16x8*)&Bk[row][seg * 8] = *(const s16x8*)(Wb + (size_t)(n0 + row) * DIM + k0 + seg * 8);
        }
        __syncthreads();

        s16x8 af[4], bfr[4];
#pragma unroll
        for (int i = 0; i < 4; ++i) af[i] = *(const s16x8*)&Ak[wr * 64 + i * 16 + l15][quad * 8];
#pragma unroll
        for (int j = 0; j < 4; ++j) bfr[j] = *(const s16x8*)&Bk[wc * 64 + j * 16 + l15][quad * 8];
#pragma unroll
        for (int i = 0; i < 4; ++i)
#pragma unroll
            for (int j = 0; j < 4; ++j)
                acc[i][j] = __builtin_amdgcn_mfma_f32_16x16x32_bf16(af[i], bfr[j], acc[i][j], 0, 0, 0);
    }

    const float SCALE = 0.17677669529663687f;  // 32^-0.5, folded into q rows

#pragma unroll
    for (int j = 0; j < 4; ++j) {
        int n = n0 + wc * 64 + j * 16 + l15;
        int head = n / QKVD;
        int rr = n - head * QKVD;
        if (rr < 64) {
            // q/k features -> qkb[bh][seq][rr]  (scalar stores, stride 64)
            float sc = rr < QKD ? SCALE : 1.0f;
#pragma unroll
            for (int i = 0; i < 4; ++i) {
                int mbase = m0 + wr * 64 + i * 16 + quad * 4;
                int bidx = mbase / L_SEQ;       // 4-run never crosses (784 % 4 == 0)
                int l0 = mbase - bidx * L_SEQ;
                size_t base = ((size_t)(bidx * NH + head) * L_SEQ + l0) * 64 + rr;
#pragma unroll
                for (int r = 0; r < 4; ++r)
                    qkb[base + (size_t)r * 64] = f2bf(acc[i][j][r] * sc);
            }
        } else {
            // v features -> vT[bh][vd][seq]  (packed s16x4 along seq)
            int vd = rr - 64;
#pragma unroll
            for (int i = 0; i < 4; ++i) {
                int mbase = m0 + wr * 64 + i * 16 + quad * 4;
                int bidx = mbase / L_SEQ;
                int l0 = mbase - bidx * L_SEQ;
                s16x4 pk;
#pragma unroll
                for (int r = 0; r < 4; ++r) pk[r] = f2bf(acc[i][j][r]);
                *(s16x4*)&vT[((size_t)(bidx * NH + head) * VD + vd) * L_SEQ + l0] = pk;
            }
        }
    }
}

// ---------------------------------------------------------------------------
// Flash attention v10: r4's verified V pipeline + Ps round-trip, with the
// Qs/Ks LDS machinery DELETED:
//  - Q fragment: one direct global load ([seq][64] layout, r3-verified).
//  - K fragments: direct global, reloaded for kt+1 right after the QK MFMAs
//    (exp+P+PV covers the latency; all 4 waves hit the same L1 lines).
//  - V: reg-staged 1 tile ahead into LDS, raw (non-draining) barriers.
//  - LDS 37.4K -> 26.1K (6 blocks/CU by LDS); K-stage 8-way-conflict writes
//    removed (the dominant SQ_LDS_BANK_CONFLICT source).
//  - s_setprio(1) around MFMA clusters (T5; independent blocks per CU).
// ---------------------------------------------------------------------------
__global__ __launch_bounds__(256, 2) void flash_attn_mfma10(const short* __restrict__ qkb,
                                                            const short* __restrict__ vT,
                                                            const float* __restrict__ biasT,
                                                            short* __restrict__ o2) {
    __shared__ short Vt[VD][68];    // [v-col][k 0..63]
    __shared__ short Ps[64][68];    // [q-row][k 0..63] wave-private rows

    const int tid = threadIdx.x;
    const int wv = tid >> 6;
    const int lane = tid & 63;
    const int quad = lane >> 4;
    const int l15 = lane & 15;

    const int h = blockIdx.x & 7;
    const int slot = blockIdx.x >> 3;
    const int b = slot / NQT;
    const int qt = slot - b * NQT;
    const int bh = b * NH + h;
    const int q0 = qt * 64;

    const short* qkp = qkb + (size_t)bh * L_SEQ * 64;
    const short* vp = vT + (size_t)bh * VD * L_SEQ;
    const float* bbase = biasT + (size_t)h * L_SEQ * L_SEQ;

    // V staging addressing (per-thread, constant across tiles)
    const int vd = tid >> 1;           // v-dim 0..127
    const int vc0 = (tid & 1) * 32;    // k-col 0 / 32
    const short* vline = vp + (size_t)vd * L_SEQ;

    // ---- Q fragment: direct global (once) ----
    int gqq = q0 + wv * 16 + l15;
    if (gqq > L_SEQ - 1) gqq = L_SEQ - 1;   // dup tail row; discarded at store
    s16x8 qfrag = *(const s16x8*)(qkp + (size_t)gqq * 64 + quad * 8);

    const int gq0 = q0 + wv * 16 + quad * 4;
    const bool vec_ok = (gq0 + 3 <= L_SEQ - 1);
    int gqr[4];
#pragma unroll
    for (int r = 0; r < 4; ++r) {
        int g = gq0 + r;
        gqr[r] = g > L_SEQ - 1 ? L_SEQ - 1 : g;
    }

    // ---- prologue: V tile 0 reg-stage, store, then issue tile-1 loads ----
    s16x8 va[4];
#pragma unroll
    for (int j = 0; j < 4; ++j) {
        int cb = vc0 + j * 8;
        va[j] = *(const s16x8*)(vline + cb);
    }
#pragma unroll
    for (int j = 0; j < 4; ++j) st_frag(&Vt[vd][vc0 + j * 8], va[j]);
    {
        int k0n = 64;
#pragma unroll
        for (int j = 0; j < 4; ++j) {
            int cb = k0n + vc0 + j * 8;
            if (cb > L_SEQ - 8) cb = L_SEQ - 8;
            va[j] = *(const s16x8*)(vline + cb);
        }
    }

    // ---- K fragments tile 0 (direct global) ----
    s16x8 kf[4];
#pragma unroll
    for (int t = 0; t < 4; ++t) {
        int row = t * 16 + l15;
        kf[t] = *(const s16x8*)(qkp + (size_t)row * 64 + 32 + quad * 8);
    }

    // ---- bias prefetch for tile 0 ----
    f32x4v bcur[4];
#pragma unroll
    for (int t = 0; t < 4; ++t) {
        int col = t * 16 + l15;
        const float* bp = bbase + (size_t)col * L_SEQ;
        if (vec_ok) {
            float4 bv = *(const float4*)(bp + gq0);
            bcur[t][0] = bv.x; bcur[t][1] = bv.y; bcur[t][2] = bv.z; bcur[t][3] = bv.w;
        } else {
#pragma unroll
            for (int r = 0; r < 4; ++r) bcur[t][r] = bp[gqr[r]];
        }
    }

    wg_barrier_lds();   // Vt tile 0 visible (prefetches stay in flight)

    f32x4v oacc[8];
#pragma unroll
    for (int vt = 0; vt < 8; ++vt) { oacc[vt][0] = 0.f; oacc[vt][1] = 0.f; oacc[vt][2] = 0.f; oacc[vt][3] = 0.f; }
    float lp[4] = {0.f, 0.f, 0.f, 0.f};

    for (int kt = 0; kt < NKT; ++kt) {
        const int k0 = kt * 64;

        // ---- QK^T: 4 MFMAs from K regs ----
        f32x4v s[4];
        __builtin_amdgcn_s_setprio(1);
#pragma unroll
        for (int t = 0; t < 4; ++t) {
            f32x4v z; z[0] = 0.f; z[1] = 0.f; z[2] = 0.f; z[3] = 0.f;
            s[t] = __builtin_amdgcn_mfma_f32_16x16x32_bf16(qfrag, kf[t], z, 0, 0, 0);
        }
        __builtin_amdgcn_s_setprio(0);
#pragma unroll
        for (int t = 0; t < 4; ++t) s[t] += bcur[t];

        // ---- reload K fragments for tile kt+1 (latency hidden by exp/P/PV) ----
        if (kt + 1 < NKT) {
            int k0n = k0 + 64;
#pragma unroll
            for (int t = 0; t < 4; ++t) {
                int row = k0n + t * 16 + l15;
                if (row > L_SEQ - 1) row = L_SEQ - 1;
                kf[t] = *(const s16x8*)(qkp + (size_t)row * 64 + 32 + quad * 8);
            }
        }
        // ---- bias prefetch for tile kt+1 ----
        if (kt + 1 < NKT) {
            int k0n = (kt + 1) * 64;
#pragma unroll
            for (int t = 0; t < 4; ++t) {
                int col = k0n + t * 16 + l15;
                if (col > L_SEQ - 1) col = L_SEQ - 1;
                const float* bp = bbase + (size_t)col * L_SEQ;
                if (vec_ok) {
                    float4 bv = *(const float4*)(bp + gq0);
                    bcur[t][0] = bv.x; bcur[t][1] = bv.y; bcur[t][2] = bv.z; bcur[t][3] = bv.w;
                } else {
#pragma unroll
                    for (int r = 0; r < 4; ++r) bcur[t][r] = bp[gqr[r]];
                }
            }
        }

        // ---- k-tail mask ----
        if (kt == NKT - 1) {
#pragma unroll
            for (int t = 0; t < 4; ++t) {
                if (k0 + t * 16 + l15 >= L_SEQ) {
                    s[t][0] = -1e30f; s[t][1] = -1e30f; s[t][2] = -1e30f; s[t][3] = -1e30f;
                }
            }
        }
        // ---- exp (scores bounded; no max shift) ----
#pragma unroll
        for (int t = 0; t < 4; ++t) {
#pragma unroll
            for (int r = 0; r < 4; ++r) {
                float p = __expf(s[t][r]);
                s[t][r] = p;
                lp[r] += p;
            }
        }
        // ---- P -> LDS bf16 (wave-private rows) ----
#pragma unroll
        for (int t = 0; t < 4; ++t)
#pragma unroll
            for (int r = 0; r < 4; ++r)
                Ps[wv * 16 + quad * 4 + r][t * 16 + l15] = f2bf(s[t][r]);

        s16x8 pf0 = ld_frag(&Ps[wv * 16 + l15][quad * 8]);
        s16x8 pf1 = ld_frag(&Ps[wv * 16 + l15][32 + quad * 8]);

        // ---- PV: 16 MFMAs (reads Vt = tile kt) ----
        __builtin_amdgcn_s_setprio(1);
#pragma unroll
        for (int vt = 0; vt < 8; ++vt) {
            int n = vt * 16 + l15;
            s16x8 b0 = ld_frag(&Vt[n][quad * 8]);
            oacc[vt] = __builtin_amdgcn_mfma_f32_16x16x32_bf16(pf0, b0, oacc[vt], 0, 0, 0);
            s16x8 b1 = ld_frag(&Vt[n][32 + quad * 8]);
            oacc[vt] = __builtin_amdgcn_mfma_f32_16x16x32_bf16(pf1, b1, oacc[vt], 0, 0, 0);
        }
        __builtin_amdgcn_s_setprio(0);

        // ---- stage V tile kt+1 (regs -> LDS), issue loads for kt+2 ----
        if (kt < NKT - 1) {
            wg_barrier_lds();   // all waves done reading Vt tile kt
#pragma unroll
            for (int j = 0; j < 4; ++j) st_frag(&Vt[vd][vc0 + j * 8], va[j]);
            if (kt + 2 < NKT) {
                int k0n = (kt + 2) * 64;
#pragma unroll
                for (int j = 0; j < 4; ++j) {
                    int cb = k0n + vc0 + j * 8;
                    if (cb > L_SEQ - 8) cb = L_SEQ - 8;
                    va[j] = *(const s16x8*)(vline + cb);
                }
            }
            wg_barrier_lds();   // tile kt+1 visible
        }
    }

    // ---- epilogue: reduce denominators across 16 lanes (once), store ----
    float inv[4];
#pragma unroll
    for (int r = 0; r < 4; ++r) {
        float ls = lp[r];
        ls += __shfl_xor(ls, 1, 16);
        ls += __shfl_xor(ls, 2, 16);
        ls += __shfl_xor(ls, 4, 16);
        ls += __shfl_xor(ls, 8, 16);
        inv[r] = 1.0f / ls;
    }
#pragma unroll
    for (int r = 0; r < 4; ++r) {
        int gq = q0 + wv * 16 + quad * 4 + r;
        if (gq >= L_SEQ) continue;
        short* dst = o2 + ((size_t)b * L_SEQ + gq) * ODIM + h * VD;
#pragma unroll
        for (int vt = 0; vt < 8; ++vt)
            dst[vt * 16 + l15] = f2bf(oacc[vt][r] * inv[r]);
    }
}

// ---------------------------------------------------------------------------
// proj GEMM (bf16 in, 128x128 tile, BK=32): out = o2 @ WprojT + bproj (fp32)
// ---------------------------------------------------------------------------
__global__ __launch_bounds__(256) void proj_gemm_mfma(const short* __restrict__ Xb,
                                                      const short* __restrict__ Wb,
                                                      const float* __restrict__ bproj,
                                                      float* __restrict__ out) {
    __shared__ short Ak[128][48];
    __shared__ short Bk[128][48];

    const int tid = threadIdx.x;
    const int wv = tid >> 6;
    const int lane = tid & 63;
    const int quad = lane >> 4;
    const int l15 = lane & 15;
    const int wr = wv >> 1, wc = wv & 1;
    const int m0 = blockIdx.x * 128;
    const int n0 = blockIdx.y * 128;

    f32x4v acc[4][4];
#pragma unroll
    for (int i = 0; i < 4; ++i)
#pragma unroll
        for (int j = 0; j < 4; ++j) { acc[i][j][0] = 0.f; acc[i][j][1] = 0.f; acc[i][j][2] = 0.f; acc[i][j][3] = 0.f; }

    for (int k0 = 0; k0 < ODIM; k0 += 32) {
        __syncthreads();
#pragma unroll
        for (int it = 0; it < 2; ++it) {
            int idx = it * 256 + tid;
            int row = idx >> 2, seg = idx & 3;
            *(s16x8*)&Ak[row][seg * 8] = *(const s16x8*)(Xb + (size_t)(m0 + row) * ODIM + k0 + seg * 8);
            *(s16x8*)&Bk[row][seg * 8] = *(const s16x8*)(Wb + (size_t)(n0 + row) * ODIM + k0 + seg * 8);
        }
        __syncthreads();

        s16x8 af[4], bfr[4];
#pragma unroll
        for (int i = 0; i < 4; ++i) af[i] = *(const s16x8*)&Ak[wr * 64 + i * 16 + l15][quad * 8];
#pragma unroll
        for (int j = 0; j < 4; ++j) bfr[j] = *(const s16x8*)&Bk[wc * 64 + j * 16 + l15][quad * 8];
#pragma unroll
        for (int i = 0; i < 4; ++i)
#pragma unroll
            for (int j = 0; j < 4; ++j)
                acc[i][j] = __builtin_amdgcn_mfma_f32_16x16x32_bf16(af[i], bfr[j], acc[i][j], 0, 0, 0);
    }

#pragma unroll
    for (int j = 0; j < 4; ++j) {
        int n = n0 + wc * 64 + j * 16 + l15;
        if (n >= DIM) continue;
        float bp = bproj[n];
#pragma unroll
        for (int i = 0; i < 4; ++i) {
            int mbase = m0 + wr * 64 + i * 16 + quad * 4;
#pragma unroll
            for (int r = 0; r < 4; ++r)
                out[(size_t)(mbase + r) * DIM + n] = acc[i][j][r] + bp;
        }
    }
}

// ---------------------------------------------------------------------------
// launch
// ---------------------------------------------------------------------------
extern "C" void kernel_launch(void* const* d_in, const int* in_sizes, int n_in,
                              void* d_out, int out_size, void* d_ws, size_t ws_size,
                              hipStream_t stream) {
    const float* x      = (const float*)d_in[0];  // (16,784,384)
    const float* Wqkv   = (const float*)d_in[1];  // (1536,384)
    const float* Wproj  = (const float*)d_in[2];  // (384,1024)
    const float* bproj  = (const float*)d_in[3];  // (384,)
    const float* table  = (const float*)d_in[4];  // (8,625)
    float* out = (float*)d_out;

    const size_t QK_SZ  = (size_t)B_SZ * NH * L_SEQ * 64;   // shorts
    const size_t VT_SZ  = (size_t)B_SZ * NH * VD * L_SEQ;   // shorts
    const size_t BI_SZ  = (size_t)NH * L_SEQ * L_SEQ;       // floats
    const size_t O2_SZ  = (size_t)B_SZ * L_SEQ * ODIM;      // shorts
    const size_t X_SZ   = (size_t)B_SZ * L_SEQ * DIM;       // shorts
    const size_t WQ_SZ  = (size_t)EDIM * DIM;               // shorts
    const size_t WP_SZ  = (size_t)DIM * ODIM;               // shorts

    short* qkb   = (short*)d_ws;
    short* vTb   = qkb + QK_SZ;
    float* bias  = (float*)(vTb + VT_SZ);
    short* o2    = (short*)(bias + BI_SZ);
    short* xb    = o2 + O2_SZ;
    short* wqkvb = xb + X_SZ;
    short* wprojb= wqkvb + WQ_SZ;
    float* wtab  = (float*)(wprojb + WP_SZ);
    int*   iyb   = (int*)(wtab + L_SEQ * 4);
    int*   ixb   = iyb + L_SEQ * 4;

    interp_tab_kernel<<<(L_SEQ + 255) / 256, 256, 0, stream>>>(wtab, iyb, ixb);

    {
        int quads = (L_SEQ * L_SEQ) / 4;               // 153664
        dim3 grid((quads + 255) / 256, NH);            // (601, 8)
        bias_kernel<<<grid, 256, 0, stream>>>(table, wtab, iyb, ixb, bias);
    }

    {
        int n0 = (int)(X_SZ / 8);
        int n1 = (int)(WQ_SZ / 8);
        int n2 = (int)(WP_SZ / 8);
        int tot = n0 + n1 + n2;
        cvt_bf16_all<<<(tot + 255) / 256, 256, 0, stream>>>(x, xb, n0, Wqkv, wqkvb, n1, Wproj, wprojb, n2);
    }

    {
        dim3 grid(12544 / 128, EDIM / 128);  // (98, 12)
        qkv_gemm_mfma<<<grid, 256, 0, stream>>>(xb, wqkvb, qkb, vTb);
    }

    flash_attn_mfma10<<<B_SZ * NH * NQT, 256, 0, stream>>>(qkb, vTb, bias, o2);

    {
        dim3 grid(12544 / 128, 3);           // N=384 -> 3 n-tiles of 128
        proj_gemm_mfma<<<grid, 256, 0, stream>>>(o2, wprojb, bproj, out);
    }
}

// Round 6
// 267.483 us; speedup vs baseline: 1.0610x; 1.0610x over previous
//
#include <hip/hip_runtime.h>
#include <cstddef>

#define L_SEQ 784
#define DIM 384
#define B_SZ 16
#define NH 8
#define QKD 32
#define VD 128
#define EDIM 1536   // NH*(2*QKD+VD)
#define RESN 25
#define NPTS 625    // RESN*RESN
#define ODIM 1024   // NH*VD
#define NQT 13      // ceil(784/64) q-tiles
#define NKT 13      // ceil(784/64) k-tiles
#define QKVD 192    // 2*QKD + VD

typedef short s16x8 __attribute__((ext_vector_type(8)));
typedef short s16x4 __attribute__((ext_vector_type(4)));
typedef float f32x4v __attribute__((ext_vector_type(4)));

__device__ __forceinline__ short f2bf(float f) {
    union { float f; unsigned u; } c; c.f = f;
    unsigned u = c.u;
    return (short)((u + 0x7FFFu + ((u >> 16) & 1u)) >> 16);
}

__device__ __forceinline__ s16x8 ld_frag(const short* p) {
    s16x4 lo = *(const s16x4*)p;
    s16x4 hi = *(const s16x4*)(p + 4);
    s16x8 r;
    r[0] = lo[0]; r[1] = lo[1]; r[2] = lo[2]; r[3] = lo[3];
    r[4] = hi[0]; r[5] = hi[1]; r[6] = hi[2]; r[7] = hi[3];
    return r;
}

__device__ __forceinline__ void st_frag(short* p, s16x8 w) {
    s16x4 lo, hi;
    lo[0] = w[0]; lo[1] = w[1]; lo[2] = w[2]; lo[3] = w[3];
    hi[0] = w[4]; hi[1] = w[5]; hi[2] = w[6]; hi[3] = w[7];
    *(s16x4*)p = lo;
    *(s16x4*)(p + 4) = hi;
}

// Raw workgroup barrier that does NOT drain vmcnt (global prefetches stay in
// flight); waits only this wave's LDS ops, then s_barrier.
__device__ __forceinline__ void wg_barrier_lds() {
    asm volatile("s_waitcnt lgkmcnt(0)" ::: "memory");
    __builtin_amdgcn_s_barrier();
    asm volatile("" ::: "memory");
}

// ---------------------------------------------------------------------------
// fp32 -> bf16 bulk convert, all three tensors in ONE launch (8 elts/thread)
// ---------------------------------------------------------------------------
__global__ __launch_bounds__(256) void cvt_bf16_all(const float* __restrict__ s0, short* __restrict__ d0, int n0,
                                                    const float* __restrict__ s1, short* __restrict__ d1, int n1,
                                                    const float* __restrict__ s2, short* __restrict__ d2, int n2) {
    int i = blockIdx.x * 256 + threadIdx.x;
    const float* s;
    short* d;
    int li;
    if (i < n0) { s = s0; d = d0; li = i; }
    else if (i < n0 + n1) { s = s1; d = d1; li = i - n0; }
    else if (i < n0 + n1 + n2) { s = s2; d = d2; li = i - n0 - n1; }
    else return;
    const float4* sp = (const float4*)(s + (size_t)li * 8);
    float4 a = sp[0], c = sp[1];
    s16x8 w;
    w[0] = f2bf(a.x); w[1] = f2bf(a.y); w[2] = f2bf(a.z); w[3] = f2bf(a.w);
    w[4] = f2bf(c.x); w[5] = f2bf(c.y); w[6] = f2bf(c.z); w[7] = f2bf(c.w);
    *(s16x8*)(d + (size_t)li * 8) = w;
}

// ---------------------------------------------------------------------------
// cubic interpolation weight (a = -0.75)
// ---------------------------------------------------------------------------
__device__ __forceinline__ float cubic_w(float x) {
    float ax = fabsf(x);
    const float a = -0.75f;
    float w1 = ((a + 2.0f) * ax - (a + 3.0f)) * ax * ax + 1.0f;
    float w2 = a * (((ax - 5.0f) * ax + 8.0f) * ax - 4.0f);
    return ax <= 1.0f ? w1 : (ax < 2.0f ? w2 : 0.0f);
}

__global__ void interp_tab_kernel(float* __restrict__ wtab,
                                  int* __restrict__ iyb,
                                  int* __restrict__ ixb) {
    int o = blockIdx.x * blockDim.x + threadIdx.x;
    if (o >= L_SEQ) return;
    const float scale = 625.0f / 784.0f;
    float src = ((float)o + 0.5f) * scale - 0.5f;
    float f = floorf(src);
    float t = src - f;
    int fi = (int)f;
    float w[4];
    w[0] = cubic_w(t + 1.0f);
    w[1] = cubic_w(t);
    w[2] = cubic_w(1.0f - t);
    w[3] = cubic_w(2.0f - t);
#pragma unroll
    for (int j = 0; j < 4; ++j) {
        int idx = fi - 1 + j;
        idx = idx < 0 ? 0 : (idx > NPTS - 1 ? NPTS - 1 : idx);
        wtab[o * 4 + j] = w[j];
        iyb[o * 4 + j] = idx / RESN;
        ixb[o * 4 + j] = idx % RESN;
    }
}

// ---------------------------------------------------------------------------
// biasT[h][p][o]: per-head table in LDS; 4 o-outputs/thread, float4 store.
// ---------------------------------------------------------------------------
__global__ __launch_bounds__(256) void bias_kernel(const float* __restrict__ table,
                                                   const float* __restrict__ wtab,
                                                   const int* __restrict__ iyb,
                                                   const int* __restrict__ ixb,
                                                   float* __restrict__ biasT) {
    __shared__ float Tl[NPTS];
    const int h = blockIdx.y;
    {
        const float* th = table + (size_t)h * NPTS;
        for (int i = threadIdx.x; i < NPTS; i += 256) Tl[i] = th[i];
    }
    __syncthreads();

    int base = (blockIdx.x * 256 + threadIdx.x) * 4;
    if (base >= L_SEQ * L_SEQ) return;
    int p = base / L_SEQ;
    int o0 = base - p * L_SEQ;

    float4 wpv = *(const float4*)(wtab + p * 4);
    int4 pyv = *(const int4*)(iyb + p * 4);
    int4 pxv = *(const int4*)(ixb + p * 4);
    float wp[4] = {wpv.x, wpv.y, wpv.z, wpv.w};
    int py[4] = {pyv.x, pyv.y, pyv.z, pyv.w};
    int px[4] = {pxv.x, pxv.y, pxv.z, pxv.w};

    float4 res;
    float* rp = (float*)&res;
#pragma unroll
    for (int u = 0; u < 4; ++u) {
        int o = o0 + u;
        float4 wov = *(const float4*)(wtab + o * 4);
        int4 oyv = *(const int4*)(iyb + o * 4);
        int4 oxv = *(const int4*)(ixb + o * 4);
        float wo[4] = {wov.x, wov.y, wov.z, wov.w};
        int oy[4] = {oyv.x, oyv.y, oyv.z, oyv.w};
        int ox[4] = {oxv.x, oxv.y, oxv.z, oxv.w};
        float s = 0.0f;
#pragma unroll
        for (int a = 0; a < 4; ++a) {
#pragma unroll
            for (int b = 0; b < 4; ++b) {
                int dy = abs(oy[a] - py[b]);
                int dx = abs(ox[a] - px[b]);
                s += wo[a] * wp[b] * Tl[dy * RESN + dx];
            }
        }
        rp[u] = s;
    }
    *(float4*)(biasT + (size_t)h * L_SEQ * L_SEQ + base) = res;
}

// ---------------------------------------------------------------------------
// qkv GEMM (bf16 in, 128x128 tile, 2x2 wave quadrants, BK=32).
// Outputs (r3/r5-verified epilogue):
//   qkb[bh][seq][64] : q feats 0..31 (pre-scaled), k feats 32..63
//   vT [bh][vd][seq] : V transposed (PV staging layout)
// ---------------------------------------------------------------------------
__global__ __launch_bounds__(256) void qkv_gemm_mfma(const short* __restrict__ Xb,
                                                     const short* __restrict__ Wb,
                                                     short* __restrict__ qkb,
                                                     short* __restrict__ vT) {
    __shared__ short Ak[128][48];
    __shared__ short Bk[128][48];

    const int tid = threadIdx.x;
    const int wv = tid >> 6;
    const int lane = tid & 63;
    const int quad = lane >> 4;
    const int l15 = lane & 15;
    const int wr = wv >> 1, wc = wv & 1;
    const int m0 = blockIdx.x * 128;
    const int n0 = blockIdx.y * 128;

    f32x4v acc[4][4];
#pragma unroll
    for (int i = 0; i < 4; ++i)
#pragma unroll
        for (int j = 0; j < 4; ++j) { acc[i][j][0] = 0.f; acc[i][j][1] = 0.f; acc[i][j][2] = 0.f; acc[i][j][3] = 0.f; }

    for (int k0 = 0; k0 < DIM; k0 += 32) {
        __syncthreads();
#pragma unroll
        for (int it = 0; it < 2; ++it) {
            int idx = it * 256 + tid;
            int row = idx >> 2, seg = idx & 3;
            *(s16x8*)&Ak[row][seg * 8] = *(const s16x8*)(Xb + (size_t)(m0 + row) * DIM + k0 + seg * 8);
            *(s16x8*)&Bk[row][seg * 8] = *(const s16x8*)(Wb + (size_t)(n0 + row) * DIM + k0 + seg * 8);
        }
        __syncthreads();

        s16x8 af[4], bfr[4];
#pragma unroll
        for (int i = 0; i < 4; ++i) af[i] = *(const s16x8*)&Ak[wr * 64 + i * 16 + l15][quad * 8];
#pragma unroll
        for (int j = 0; j < 4; ++j) bfr[j] = *(const s16x8*)&Bk[wc * 64 + j * 16 + l15][quad * 8];
#pragma unroll
        for (int i = 0; i < 4; ++i)
#pragma unroll
            for (int j = 0; j < 4; ++j)
                acc[i][j] = __builtin_amdgcn_mfma_f32_16x16x32_bf16(af[i], bfr[j], acc[i][j], 0, 0, 0);
    }

    const float SCALE = 0.17677669529663687f;  // 32^-0.5, folded into q rows

#pragma unroll
    for (int j = 0; j < 4; ++j) {
        int n = n0 + wc * 64 + j * 16 + l15;
        int head = n / QKVD;
        int rr = n - head * QKVD;
        if (rr < 64) {
            float sc = rr < QKD ? SCALE : 1.0f;
#pragma unroll
            for (int i = 0; i < 4; ++i) {
                int mbase = m0 + wr * 64 + i * 16 + quad * 4;
                int bidx = mbase / L_SEQ;       // 4-run never crosses (784 % 4 == 0)
                int l0 = mbase - bidx * L_SEQ;
                size_t base = ((size_t)(bidx * NH + head) * L_SEQ + l0) * 64 + rr;
#pragma unroll
                for (int r = 0; r < 4; ++r)
                    qkb[base + (size_t)r * 64] = f2bf(acc[i][j][r] * sc);
            }
        } else {
            int vd = rr - 64;
#pragma unroll
            for (int i = 0; i < 4; ++i) {
                int mbase = m0 + wr * 64 + i * 16 + quad * 4;
                int bidx = mbase / L_SEQ;
                int l0 = mbase - bidx * L_SEQ;
                s16x4 pk;
#pragma unroll
                for (int r = 0; r < 4; ++r) pk[r] = f2bf(acc[i][j][r]);
                *(s16x4*)&vT[((size_t)(bidx * NH + head) * VD + vd) * L_SEQ + l0] = pk;
            }
        }
    }
}

// ---------------------------------------------------------------------------
// Flash attention v11: swapped QK^T (r3-verified) + LDS V double-buffer with
// ONE lgkm-barrier per tile (new) + reg-staged V pipeline (r4/r5-verified).
//  - lane owns one q-row: P pack = 4x ds_write_b64; denom = per-lane scalar;
//    bias read = lane's own row (bias symmetric, r3-verified).
//  - Vt[2]: stage tile kt+1 into idle buffer BEFORE PV(kt) -> no WAR barrier;
//    single barrier per tile lets waves slide a full tile against each other.
// ---------------------------------------------------------------------------
__global__ __launch_bounds__(256, 2) void flash_attn_mfma11(const short* __restrict__ qkb,
                                                            const short* __restrict__ vT,
                                                            const float* __restrict__ biasT,
                                                            short* __restrict__ o2) {
    __shared__ short Vt[2][VD][68];  // [buf][v-col][k 0..63]
    __shared__ short Ps[64][72];     // [q-row][k 0..63] wave-private; 144B row (16B-aligned)

    const int tid = threadIdx.x;
    const int wv = tid >> 6;
    const int lane = tid & 63;
    const int quad = lane >> 4;
    const int l15 = lane & 15;

    const int h = blockIdx.x & 7;
    const int slot = blockIdx.x >> 3;
    const int b = slot / NQT;
    const int qt = slot - b * NQT;
    const int bh = b * NH + h;
    const int q0 = qt * 64;

    const short* qkp = qkb + (size_t)bh * L_SEQ * 64;
    const short* vp = vT + (size_t)bh * VD * L_SEQ;

    // V staging addressing (per-thread, constant across tiles)
    const int vd = tid >> 1;           // v-dim 0..127
    const int vc0 = (tid & 1) * 32;    // k-col 0 / 32
    const short* vline = vp + (size_t)vd * L_SEQ;

    // ---- Q fragment (B operand): lane l15 = q-row, quad*8 = d ----
    int gqq = q0 + wv * 16 + l15;
    if (gqq > L_SEQ - 1) gqq = L_SEQ - 1;   // dup tail row; discarded at store
    const float* brow = biasT + (size_t)h * L_SEQ * L_SEQ + (size_t)gqq * L_SEQ;
    s16x8 qfrag = *(const s16x8*)(qkp + (size_t)gqq * 64 + quad * 8);

    // ---- prologue: V tile 0 -> Vt[0]; issue tile-1 loads ----
    s16x8 va[4];
#pragma unroll
    for (int j = 0; j < 4; ++j) va[j] = *(const s16x8*)(vline + vc0 + j * 8);
#pragma unroll
    for (int j = 0; j < 4; ++j) st_frag(&Vt[0][vd][vc0 + j * 8], va[j]);
    {
#pragma unroll
        for (int j = 0; j < 4; ++j) {
            int cb = 64 + vc0 + j * 8;
            if (cb > L_SEQ - 8) cb = L_SEQ - 8;
            va[j] = *(const s16x8*)(vline + cb);
        }
    }

    // ---- K fragments (A operand) + bias row-slices for tile 0 ----
    s16x8 kf[4];
    f32x4v bcur[4];
#pragma unroll
    for (int t = 0; t < 4; ++t) {
        kf[t] = *(const s16x8*)(qkp + (size_t)(t * 16 + l15) * 64 + 32 + quad * 8);
        float4 bv = *(const float4*)(brow + t * 16 + quad * 4);
        bcur[t][0] = bv.x; bcur[t][1] = bv.y; bcur[t][2] = bv.z; bcur[t][3] = bv.w;
    }

    wg_barrier_lds();   // Vt[0] visible; global prefetches stay in flight

    f32x4v oacc[8];
#pragma unroll
    for (int vt = 0; vt < 8; ++vt) { oacc[vt][0] = 0.f; oacc[vt][1] = 0.f; oacc[vt][2] = 0.f; oacc[vt][3] = 0.f; }
    float lp = 0.f;     // this lane's q-row partial denominator
    int buf = 0;

    for (int kt = 0; kt < NKT; ++kt) {
        const int k0 = kt * 64;

        // ---- QK^T swapped: D[m=k][n=q]; lane holds q=l15, k=t*16+quad*4+r ----
        f32x4v s[4];
        __builtin_amdgcn_s_setprio(1);
#pragma unroll
        for (int t = 0; t < 4; ++t) {
            f32x4v z; z[0] = 0.f; z[1] = 0.f; z[2] = 0.f; z[3] = 0.f;
            s[t] = __builtin_amdgcn_mfma_f32_16x16x32_bf16(kf[t], qfrag, z, 0, 0, 0);
        }
        __builtin_amdgcn_s_setprio(0);
#pragma unroll
        for (int t = 0; t < 4; ++t) s[t] += bcur[t];

        // ---- prefetch K + bias for tile kt+1 (hidden under exp/P/PV) ----
        if (kt + 1 < NKT) {
            int k0n = k0 + 64;
#pragma unroll
            for (int t = 0; t < 4; ++t) {
                int row = k0n + t * 16 + l15;
                if (row > L_SEQ - 1) row = L_SEQ - 1;
                kf[t] = *(const s16x8*)(qkp + (size_t)row * 64 + 32 + quad * 8);
                int c = k0n + t * 16 + quad * 4;
                if (c > L_SEQ - 4) c = L_SEQ - 4;
                float4 bv = *(const float4*)(brow + c);
                bcur[t][0] = bv.x; bcur[t][1] = bv.y; bcur[t][2] = bv.z; bcur[t][3] = bv.w;
            }
        }

        // ---- k-tail mask (uniform per (t,quad): 784 % 4 == 0) ----
        if (kt == NKT - 1) {
#pragma unroll
            for (int t = 0; t < 4; ++t) {
                if (k0 + t * 16 + quad * 4 >= L_SEQ) {
                    s[t][0] = -1e30f; s[t][1] = -1e30f; s[t][2] = -1e30f; s[t][3] = -1e30f;
                }
            }
        }

        // ---- exp + pack + packed P store (4x ds_write_b64, wave-private) ----
#pragma unroll
        for (int t = 0; t < 4; ++t) {
            s16x4 pk;
#pragma unroll
            for (int r = 0; r < 4; ++r) {
                float p = __expf(s[t][r]);
                lp += p;
                pk[r] = f2bf(p);
            }
            *(s16x4*)&Ps[wv * 16 + l15][t * 16 + quad * 4] = pk;
        }

        // ---- stage V tile kt+1 into IDLE buffer (no WAR barrier needed) ----
        if (kt + 1 < NKT) {
#pragma unroll
            for (int j = 0; j < 4; ++j) st_frag(&Vt[buf ^ 1][vd][vc0 + j * 8], va[j]);
            if (kt + 2 < NKT) {
                int k0n2 = (kt + 2) * 64;
#pragma unroll
                for (int j = 0; j < 4; ++j) {
                    int cb = k0n2 + vc0 + j * 8;
                    if (cb > L_SEQ - 8) cb = L_SEQ - 8;
                    va[j] = *(const s16x8*)(vline + cb);
                }
            }
        }

        // ---- P fragments (same-wave LDS ordering; no barrier) ----
        s16x8 pf0 = *(const s16x8*)&Ps[wv * 16 + l15][quad * 8];
        s16x8 pf1 = *(const s16x8*)&Ps[wv * 16 + l15][32 + quad * 8];

        // ---- PV: 16 MFMAs reading Vt[buf] ----
        __builtin_amdgcn_s_setprio(1);
#pragma unroll
        for (int vt = 0; vt < 8; ++vt) {
            int n = vt * 16 + l15;
            s16x8 b0 = ld_frag(&Vt[buf][n][quad * 8]);
            oacc[vt] = __builtin_amdgcn_mfma_f32_16x16x32_bf16(pf0, b0, oacc[vt], 0, 0, 0);
            s16x8 b1 = ld_frag(&Vt[buf][n][32 + quad * 8]);
            oacc[vt] = __builtin_amdgcn_mfma_f32_16x16x32_bf16(pf1, b1, oacc[vt], 0, 0, 0);
        }
        __builtin_amdgcn_s_setprio(0);

        // ---- single barrier per tile: V(kt+1) writes visible to all waves ----
        if (kt + 1 < NKT) {
            wg_barrier_lds();
            buf ^= 1;
        }
    }

    // ---- epilogue (r3-verified): row sum across the 4 quads, store ----
    float lsum = lp;
    lsum += __shfl_xor(lsum, 16);
    lsum += __shfl_xor(lsum, 32);
    float inv[4];
#pragma unroll
    for (int r = 0; r < 4; ++r)
        inv[r] = 1.0f / __shfl(lsum, quad * 4 + r, 16);

#pragma unroll
    for (int r = 0; r < 4; ++r) {
        int gqs = q0 + wv * 16 + quad * 4 + r;
        if (gqs >= L_SEQ) continue;
        short* dst = o2 + ((size_t)b * L_SEQ + gqs) * ODIM + h * VD;
#pragma unroll
        for (int vt = 0; vt < 8; ++vt)
            dst[vt * 16 + l15] = f2bf(oacc[vt][r] * inv[r]);
    }
}

// ---------------------------------------------------------------------------
// proj GEMM (bf16 in, 128x128 tile, BK=32): out = o2 @ WprojT + bproj (fp32)
// ---------------------------------------------------------------------------
__global__ __launch_bounds__(256) void proj_gemm_mfma(const short* __restrict__ Xb,
                                                      const short* __restrict__ Wb,
                                                      const float* __restrict__ bproj,
                                                      float* __restrict__ out) {
    __shared__ short Ak[128][48];
    __shared__ short Bk[128][48];

    const int tid = threadIdx.x;
    const int wv = tid >> 6;
    const int lane = tid & 63;
    const int quad = lane >> 4;
    const int l15 = lane & 15;
    const int wr = wv >> 1, wc = wv & 1;
    const int m0 = blockIdx.x * 128;
    const int n0 = blockIdx.y * 128;

    f32x4v acc[4][4];
#pragma unroll
    for (int i = 0; i < 4; ++i)
#pragma unroll
        for (int j = 0; j < 4; ++j) { acc[i][j][0] = 0.f; acc[i][j][1] = 0.f; acc[i][j][2] = 0.f; acc[i][j][3] = 0.f; }

    for (int k0 = 0; k0 < ODIM; k0 += 32) {
        __syncthreads();
#pragma unroll
        for (int it = 0; it < 2; ++it) {
            int idx = it * 256 + tid;
            int row = idx >> 2, seg = idx & 3;
            *(s16x8*)&Ak[row][seg * 8] = *(const s16x8*)(Xb + (size_t)(m0 + row) * ODIM + k0 + seg * 8);
            *(s16x8*)&Bk[row][seg * 8] = *(const s16x8*)(Wb + (size_t)(n0 + row) * ODIM + k0 + seg * 8);
        }
        __syncthreads();

        s16x8 af[4], bfr[4];
#pragma unroll
        for (int i = 0; i < 4; ++i) af[i] = *(const s16x8*)&Ak[wr * 64 + i * 16 + l15][quad * 8];
#pragma unroll
        for (int j = 0; j < 4; ++j) bfr[j] = *(const s16x8*)&Bk[wc * 64 + j * 16 + l15][quad * 8];
#pragma unroll
        for (int i = 0; i < 4; ++i)
#pragma unroll
            for (int j = 0; j < 4; ++j)
                acc[i][j] = __builtin_amdgcn_mfma_f32_16x16x32_bf16(af[i], bfr[j], acc[i][j], 0, 0, 0);
    }

#pragma unroll
    for (int j = 0; j < 4; ++j) {
        int n = n0 + wc * 64 + j * 16 + l15;
        if (n >= DIM) continue;
        float bp = bproj[n];
#pragma unroll
        for (int i = 0; i < 4; ++i) {
            int mbase = m0 + wr * 64 + i * 16 + quad * 4;
#pragma unroll
            for (int r = 0; r < 4; ++r)
                out[(size_t)(mbase + r) * DIM + n] = acc[i][j][r] + bp;
        }
    }
}

// ---------------------------------------------------------------------------
// launch
// ---------------------------------------------------------------------------
extern "C" void kernel_launch(void* const* d_in, const int* in_sizes, int n_in,
                              void* d_out, int out_size, void* d_ws, size_t ws_size,
                              hipStream_t stream) {
    const float* x      = (const float*)d_in[0];  // (16,784,384)
    const float* Wqkv   = (const float*)d_in[1];  // (1536,384)
    const float* Wproj  = (const float*)d_in[2];  // (384,1024)
    const float* bproj  = (const float*)d_in[3];  // (384,)
    const float* table  = (const float*)d_in[4];  // (8,625)
    float* out = (float*)d_out;

    const size_t QK_SZ  = (size_t)B_SZ * NH * L_SEQ * 64;   // shorts
    const size_t VT_SZ  = (size_t)B_SZ * NH * VD * L_SEQ;   // shorts
    const size_t BI_SZ  = (size_t)NH * L_SEQ * L_SEQ;       // floats
    const size_t O2_SZ  = (size_t)B_SZ * L_SEQ * ODIM;      // shorts
    const size_t X_SZ   = (size_t)B_SZ * L_SEQ * DIM;       // shorts
    const size_t WQ_SZ  = (size_t)EDIM * DIM;               // shorts
    const size_t WP_SZ  = (size_t)DIM * ODIM;               // shorts

    short* qkb   = (short*)d_ws;
    short* vTb   = qkb + QK_SZ;
    float* bias  = (float*)(vTb + VT_SZ);
    short* o2    = (short*)(bias + BI_SZ);
    short* xb    = o2 + O2_SZ;
    short* wqkvb = xb + X_SZ;
    short* wprojb= wqkvb + WQ_SZ;
    float* wtab  = (float*)(wprojb + WP_SZ);
    int*   iyb   = (int*)(wtab + L_SEQ * 4);
    int*   ixb   = iyb + L_SEQ * 4;

    interp_tab_kernel<<<(L_SEQ + 255) / 256, 256, 0, stream>>>(wtab, iyb, ixb);

    {
        int quads = (L_SEQ * L_SEQ) / 4;               // 153664
        dim3 grid((quads + 255) / 256, NH);            // (601, 8)
        bias_kernel<<<grid, 256, 0, stream>>>(table, wtab, iyb, ixb, bias);
    }

    {
        int n0 = (int)(X_SZ / 8);
        int n1 = (int)(WQ_SZ / 8);
        int n2 = (int)(WP_SZ / 8);
        int tot = n0 + n1 + n2;
        cvt_bf16_all<<<(tot + 255) / 256, 256, 0, stream>>>(x, xb, n0, Wqkv, wqkvb, n1, Wproj, wprojb, n2);
    }

    {
        dim3 grid(12544 / 128, EDIM / 128);  // (98, 12)
        qkv_gemm_mfma<<<grid, 256, 0, stream>>>(xb, wqkvb, qkb, vTb);
    }

    flash_attn_mfma11<<<B_SZ * NH * NQT, 256, 0, stream>>>(qkb, vTb, bias, o2);

    {
        dim3 grid(12544 / 128, 3);           // N=384 -> 3 n-tiles of 128
        proj_gemm_mfma<<<grid, 256, 0, stream>>>(o2, wprojb, bproj, out);
    }
}